// Round 2
// baseline (317.369 us; speedup 1.0000x reference)
//
#include <hip/hip_runtime.h>
#include <math.h>

#define NS 96
#define SM1 95
#define NC 32
#define REPS 1e-10f

// ---------------------------------------------------------------------------
// DPP helpers (gfx9/CDNA encodings; valid on gfx950).
// update_dpp: lanes with no valid source lane (or rows masked off) get `oldv`.
// All DPP use below is in FULL-EXEC regions only (validated by round-1 rgb).
// ---------------------------------------------------------------------------
#define DPP_ROW_SHR(n)  (0x110 + (n))
#define DPP_ROW_ROR(n)  (0x120 + (n))
#define DPP_WF_SR1      0x138          // whole-wave shift right by 1
#define DPP_ROW_BCAST15 0x142
#define DPP_ROW_BCAST31 0x143

template <int CTRL, int ROW_MASK>
__device__ __forceinline__ float dppf(float x, float oldv) {
    return __int_as_float(__builtin_amdgcn_update_dpp(
        __float_as_int(oldv), __float_as_int(x), CTRL, ROW_MASK, 0xF, false));
}

__device__ __forceinline__ float rdlanef(float x, int lane) {
    return __int_as_float(__builtin_amdgcn_readlane(__float_as_int(x), lane));
}

// Wave64 inclusive product scan: Hillis-Steele within 16-lane rows, then
// row_bcast15 (rows 1,3) and row_bcast31 (rows 2,3) merge across rows.
// Invalid lanes multiply by 1.0 (old), so no exec-mask games needed.
__device__ __forceinline__ float scan_prod64(float x) {
    x *= dppf<DPP_ROW_SHR(1), 0xF>(x, 1.0f);
    x *= dppf<DPP_ROW_SHR(2), 0xF>(x, 1.0f);
    x *= dppf<DPP_ROW_SHR(4), 0xF>(x, 1.0f);
    x *= dppf<DPP_ROW_SHR(8), 0xF>(x, 1.0f);
    x *= dppf<DPP_ROW_BCAST15, 0xA>(x, 1.0f);
    x *= dppf<DPP_ROW_BCAST31, 0xC>(x, 1.0f);
    return x;  // lane i: prod x[0..i]
}

// ---------------------------------------------------------------------------
// Fused kernel: one WAVE per ray (4 rays per 256-thread block).
//   Load order: scalar dep/den loads issued FIRST (vmcnt is in-order, so the
//   scan waits at vmcnt(12) and runs under the 12 color-load latencies).
//   Scan/shift on DPP (VALU pipe); wsum/dsum reduced with the PROVEN
//   __shfl_xor butterfly in the full-exec region (the round-1 DPP row-sum +
//   in-branch readlane combine produced garbage depth — reverted).
//   Zero LDS, zero __syncthreads, ZERO workspace.
// ---------------------------------------------------------------------------
__global__ __launch_bounds__(256) void raymarch_fused(
    const float* __restrict__ colors,     // [rays, 96, 32]
    const float* __restrict__ densities,  // [rays, 96]
    const float* __restrict__ depths,     // [rays, 96]
    float* __restrict__ out_rgb,          // [rays, 32]
    float* __restrict__ out_depth,        // [rays] (unclipped, nan->inf)
    float* __restrict__ out_w,            // [rays, 95]
    float* __restrict__ out_alpha,        // [rays, 95]
    float* __restrict__ out_wbg)          // [rays]
{
    const int ray  = blockIdx.x * 4 + (threadIdx.x >> 6);
    const int lane = threadIdx.x & 63;

    // ---- scan-side scalar loads FIRST (neighbors loaded directly: same
    //      cache lines as dep[lane], no shuffle patch needed) ----
    const float* dep = depths + (size_t)ray * NS;
    const float* den = densities + (size_t)ray * NS;

    const bool hi = (lane < 31);
    float dep0 = dep[lane];
    float den0 = den[lane];
    float dn0  = dep[lane + 1];      // lane+1 <= 64 < 96, always valid
    float en0  = den[lane + 1];
    float dep1 = 0.0f, den1 = 0.0f, dn1 = 0.0f, en1 = 0.0f;
    if (hi) {
        dep1 = dep[64 + lane];
        den1 = den[64 + lane];
        dn1  = dep[65 + lane];       // up to dep[95]
        en1  = den[65 + lane];
    }

    // ---- now issue the heavy color loads (12 x 1KiB coalesced waves) ----
    const float4* col4 = (const float4*)(colors + (size_t)ray * NS * NC);
    float4 v[12];
    #pragma unroll
    for (int k = 0; k < 12; ++k) {
        v[k] = col4[lane + 64 * k];
    }

    // ---- Phase A: alpha / transmittance scan (runs under color latency) ----
    float dm0  = 0.5f * (den0 + en0) - 1.0f;
    float sp0  = fmaxf(dm0, 0.0f) + __logf(1.0f + __expf(-fabsf(dm0)));
    float a0   = 1.0f - __expf(-sp0 * (dn0 - dep0));
    float mid0 = 0.5f * (dep0 + dn0);

    float a1 = 0.0f, mid1 = 0.0f;
    if (hi) {
        float dm1 = 0.5f * (den1 + en1) - 1.0f;
        float sp1 = fmaxf(dm1, 0.0f) + __logf(1.0f + __expf(-fabsf(dm1)));
        a1   = 1.0f - __expf(-sp1 * (dn1 - dep1));
        mid1 = 0.5f * (dep1 + dn1);
    }

    float oma0 = 1.0f - a0 + REPS;
    float oma1 = hi ? (1.0f - a1 + REPS) : 1.0f;

    float x = scan_prod64(oma0);                 // prod oma[0..lane]
    float y = scan_prod64(oma1);                 // prod oma1[0..lane]
    float total0 = rdlanef(x, 63);               // prod oma[0..63]

    float T0 = dppf<DPP_WF_SR1, 0xF>(x, 1.0f);   // exclusive: lane0 -> 1.0
    float w0 = a0 * T0;
    float T1 = dppf<DPP_WF_SR1, 0xF>(y, 1.0f) * total0;
    float w1 = a1 * T1;                          // a1 == 0 for lane >= 31

    float wbg = rdlanef(y, 30) * total0;         // prod oma[0..94]

    // coeff[t] = 0.5*(w[t-1] + w[t]), w[-1] = w[95] = 0
    float w63 = rdlanef(w0, 63);
    float c0 = 0.5f * (dppf<DPP_WF_SR1, 0xF>(w0, 0.0f) + w0);   // t = lane
    float c1 = 0.5f * (dppf<DPP_WF_SR1, 0xF>(w1, w63) + w1);    // t = 64+lane

    // weight / depth reductions: PROVEN shfl_xor butterfly, full-exec region
    float wsum = w0 + w1;
    float dsum = fmaf(w0, mid0, w1 * mid1);      // w1 == mid1 == 0 for lane>=31
    #pragma unroll
    for (int off = 32; off > 0; off >>= 1) {
        wsum += __shfl_xor(wsum, off);
        dsum += __shfl_xor(dsum, off);
    }

    // ---- scan-side stores (coalesced) ----
    const size_t b95 = (size_t)ray * SM1;
    out_alpha[b95 + lane] = a0;
    out_w[b95 + lane]     = w0;
    if (hi) {
        out_alpha[b95 + 64 + lane] = a1;
        out_w[b95 + 64 + lane]     = w1;
    }
    if (lane == 0) {
        out_wbg[ray] = wbg;
        float cd = dsum / wsum;
        if (cd != cd) cd = __builtin_inff();     // NaN -> inf; clip in finalize
        out_depth[ray] = cd;
    }

    // ---- Phase B: color accumulate ----
    // lane = srow*8 + g; sample t = srow + 8k; float4 index = lane + 64k.
    const int srow = lane >> 3;
    float4 acc = {0.0f, 0.0f, 0.0f, 0.0f};
    #pragma unroll
    for (int k = 0; k < 8; ++k) {
        float c = __shfl(c0, srow + 8 * k);          // t = srow + 8k < 64
        acc.x = fmaf(c, v[k].x, acc.x);
        acc.y = fmaf(c, v[k].y, acc.y);
        acc.z = fmaf(c, v[k].z, acc.z);
        acc.w = fmaf(c, v[k].w, acc.w);
    }
    #pragma unroll
    for (int k = 8; k < 12; ++k) {
        float c = __shfl(c1, srow + 8 * (k - 8));    // t = 64 + srow + 8(k-8)
        acc.x = fmaf(c, v[k].x, acc.x);
        acc.y = fmaf(c, v[k].y, acc.y);
        acc.z = fmaf(c, v[k].z, acc.z);
        acc.w = fmaf(c, v[k].w, acc.w);
    }

    // reduce across the 8 srow groups: ^8 via DPP row_ror:8, then ^16, ^32
    acc.x += dppf<DPP_ROW_ROR(8), 0xF>(acc.x, 0.0f);
    acc.y += dppf<DPP_ROW_ROR(8), 0xF>(acc.y, 0.0f);
    acc.z += dppf<DPP_ROW_ROR(8), 0xF>(acc.z, 0.0f);
    acc.w += dppf<DPP_ROW_ROR(8), 0xF>(acc.w, 0.0f);
    #pragma unroll
    for (int m = 16; m < 64; m <<= 1) {
        acc.x += __shfl_xor(acc.x, m);
        acc.y += __shfl_xor(acc.y, m);
        acc.z += __shfl_xor(acc.z, m);
        acc.w += __shfl_xor(acc.w, m);
    }

    if (lane < 8) {  // g = lane; 8 lanes store 128B contiguous per ray
        float4 o;
        o.x = 2.0f * acc.x - 1.0f;
        o.y = 2.0f * acc.y - 1.0f;
        o.z = 2.0f * acc.z - 1.0f;
        o.w = 2.0f * acc.w - 1.0f;
        ((float4*)(out_rgb + (size_t)ray * NC))[lane] = o;
    }
}

// ---------------------------------------------------------------------------
// Finalize: global min/max of depths = endpoints (sorted along S), read
// directly from the input (L2-resident after kernel 1). ZERO workspace.
// ---------------------------------------------------------------------------
__global__ __launch_bounds__(256) void raymarch_finalize(
    const float* __restrict__ depths,
    float* __restrict__ out_depth,
    int rays)
{
    const int tid = threadIdx.x;
    float mn = __builtin_inff();
    float mx = -__builtin_inff();
    for (int r = tid; r < rays; r += 256) {
        const float* dp = depths + (size_t)r * NS;
        mn = fminf(mn, dp[0]);
        mx = fmaxf(mx, dp[SM1]);
    }
    #pragma unroll
    for (int off = 1; off < 64; off <<= 1) {
        mn = fminf(mn, __shfl_xor(mn, off));
        mx = fmaxf(mx, __shfl_xor(mx, off));
    }
    __shared__ float s_mn[4];
    __shared__ float s_mx[4];
    if ((tid & 63) == 0) {
        s_mn[tid >> 6] = mn;
        s_mx[tid >> 6] = mx;
    }
    __syncthreads();
    const float dmin = fminf(fminf(s_mn[0], s_mn[1]), fminf(s_mn[2], s_mn[3]));
    const float dmax = fmaxf(fmaxf(s_mx[0], s_mx[1]), fmaxf(s_mx[2], s_mx[3]));

    const int r = blockIdx.x * 256 + tid;
    if (r < rays) {
        float cd = out_depth[r];
        out_depth[r] = fminf(fmaxf(cd, dmin), dmax);  // clip(inf) -> dmax
    }
}

extern "C" void kernel_launch(void* const* d_in, const int* in_sizes, int n_in,
                              void* d_out, int out_size, void* d_ws, size_t ws_size,
                              hipStream_t stream) {
    (void)d_ws; (void)ws_size; (void)n_in; (void)out_size;

    const float* colors    = (const float*)d_in[0];
    const float* densities = (const float*)d_in[1];
    const float* depths    = (const float*)d_in[2];

    const int rays = in_sizes[2] / NS;  // B*R = 16384

    float* out = (float*)d_out;
    float* out_rgb   = out;                                   // rays*32
    float* out_depth = out_rgb + (size_t)rays * NC;           // rays
    float* out_w     = out_depth + rays;                      // rays*95
    float* out_alpha = out_w + (size_t)rays * SM1;            // rays*95
    float* out_wbg   = out_alpha + (size_t)rays * SM1;        // rays

    raymarch_fused<<<rays / 4, 256, 0, stream>>>(
        colors, densities, depths,
        out_rgb, out_depth, out_w, out_alpha, out_wbg);

    raymarch_finalize<<<(rays + 255) / 256, 256, 0, stream>>>(
        depths, out_depth, rays);
}

// Round 5
// 289.634 us; speedup vs baseline: 1.0958x; 1.0958x over previous
//
#include <hip/hip_runtime.h>
#include <math.h>

#define NS 96
#define SM1 95
#define NC 32
#define REPS 1e-10f

// Native clang vector type — __builtin_nontemporal_load requires scalar or
// native vector pointers (HIP_vector_type<float,4> is rejected; round-3 fix).
typedef float floatx4 __attribute__((ext_vector_type(4)));

// ---------------------------------------------------------------------------
// DPP helpers (gfx9/CDNA encodings; valid on gfx950).
// update_dpp: lanes with no valid source lane (or rows masked off) get `oldv`.
// All DPP use below is in FULL-EXEC regions only (validated rounds 1-2).
// ---------------------------------------------------------------------------
#define DPP_ROW_SHR(n)  (0x110 + (n))
#define DPP_ROW_ROR(n)  (0x120 + (n))
#define DPP_WF_SR1      0x138          // whole-wave shift right by 1
#define DPP_ROW_BCAST15 0x142
#define DPP_ROW_BCAST31 0x143

template <int CTRL, int ROW_MASK>
__device__ __forceinline__ float dppf(float x, float oldv) {
    return __int_as_float(__builtin_amdgcn_update_dpp(
        __float_as_int(oldv), __float_as_int(x), CTRL, ROW_MASK, 0xF, false));
}

__device__ __forceinline__ float rdlanef(float x, int lane) {
    return __int_as_float(__builtin_amdgcn_readlane(__float_as_int(x), lane));
}

// Wave64 inclusive product scan: Hillis-Steele within 16-lane rows, then
// row_bcast15 (rows 1,3) and row_bcast31 (rows 2,3) merge across rows.
__device__ __forceinline__ float scan_prod64(float x) {
    x *= dppf<DPP_ROW_SHR(1), 0xF>(x, 1.0f);
    x *= dppf<DPP_ROW_SHR(2), 0xF>(x, 1.0f);
    x *= dppf<DPP_ROW_SHR(4), 0xF>(x, 1.0f);
    x *= dppf<DPP_ROW_SHR(8), 0xF>(x, 1.0f);
    x *= dppf<DPP_ROW_BCAST15, 0xA>(x, 1.0f);
    x *= dppf<DPP_ROW_BCAST31, 0xC>(x, 1.0f);
    return x;  // lane i: prod x[0..i]
}

// ---------------------------------------------------------------------------
// Fused kernel: one WAVE per ray (4 rays per 256-thread block).
//   Load order: scalar dep/den loads FIRST (in-order vmcnt -> scan runs under
//   the 12 color-load latencies). Scan/shift on DPP (VALU pipe). wsum/dsum
//   reduced with the proven __shfl_xor butterfly in the full-exec region.
//   Colors loaded NON-TEMPORAL (192 MiB streamed once — keep L2/L3 clean);
//   out_w / out_alpha stored non-temporal (write-once streams).
//   dmin/dmax endpoints staged to workspace (fills are unconditional, so the
//   workspace is free — round-2's strided endpoint gather in finalize was a
//   +14 us regression, reverted).
// ---------------------------------------------------------------------------
__global__ __launch_bounds__(256) void raymarch_fused(
    const float* __restrict__ colors,     // [rays, 96, 32]
    const float* __restrict__ densities,  // [rays, 96]
    const float* __restrict__ depths,     // [rays, 96]
    float* __restrict__ out_rgb,          // [rays, 32]
    float* __restrict__ out_depth,        // [rays] (unclipped, nan->inf)
    float* __restrict__ out_w,            // [rays, 95]
    float* __restrict__ out_alpha,        // [rays, 95]
    float* __restrict__ out_wbg,          // [rays]
    float* __restrict__ ws_d0,            // [rays] dep[0]
    float* __restrict__ ws_d1)            // [rays] dep[95]
{
    const int ray  = blockIdx.x * 4 + (threadIdx.x >> 6);
    const int lane = threadIdx.x & 63;

    // ---- scan-side scalar loads FIRST (neighbors loaded directly: same
    //      cache lines as dep[lane], no shuffle patch needed) ----
    const float* dep = depths + (size_t)ray * NS;
    const float* den = densities + (size_t)ray * NS;

    const bool hi = (lane < 31);
    float dep0 = dep[lane];
    float den0 = den[lane];
    float dn0  = dep[lane + 1];      // lane+1 <= 64 < 96, always valid
    float en0  = den[lane + 1];
    float dep1 = 0.0f, den1 = 0.0f, dn1 = 0.0f, en1 = 0.0f;
    if (hi) {
        dep1 = dep[64 + lane];
        den1 = den[64 + lane];
        dn1  = dep[65 + lane];       // up to dep[95]
        en1  = den[65 + lane];
    }

    // ---- heavy color loads (12 x 1KiB coalesced, NON-TEMPORAL) ----
    const floatx4* col4 = (const floatx4*)(colors + (size_t)ray * NS * NC);
    floatx4 v[12];
    #pragma unroll
    for (int k = 0; k < 12; ++k) {
        v[k] = __builtin_nontemporal_load(col4 + lane + 64 * k);
    }

    // ---- Phase A: alpha / transmittance scan (runs under color latency) ----
    float dm0  = 0.5f * (den0 + en0) - 1.0f;
    float sp0  = fmaxf(dm0, 0.0f) + __logf(1.0f + __expf(-fabsf(dm0)));
    float a0   = 1.0f - __expf(-sp0 * (dn0 - dep0));
    float mid0 = 0.5f * (dep0 + dn0);

    float a1 = 0.0f, mid1 = 0.0f;
    if (hi) {
        float dm1 = 0.5f * (den1 + en1) - 1.0f;
        float sp1 = fmaxf(dm1, 0.0f) + __logf(1.0f + __expf(-fabsf(dm1)));
        a1   = 1.0f - __expf(-sp1 * (dn1 - dep1));
        mid1 = 0.5f * (dep1 + dn1);
    }

    float oma0 = 1.0f - a0 + REPS;
    float oma1 = hi ? (1.0f - a1 + REPS) : 1.0f;

    float x = scan_prod64(oma0);                 // prod oma[0..lane]
    float y = scan_prod64(oma1);                 // prod oma1[0..lane]
    float total0 = rdlanef(x, 63);               // prod oma[0..63]

    float T0 = dppf<DPP_WF_SR1, 0xF>(x, 1.0f);   // exclusive: lane0 -> 1.0
    float w0 = a0 * T0;
    float T1 = dppf<DPP_WF_SR1, 0xF>(y, 1.0f) * total0;
    float w1 = a1 * T1;                          // a1 == 0 for lane >= 31

    float wbg = rdlanef(y, 30) * total0;         // prod oma[0..94]

    // coeff[t] = 0.5*(w[t-1] + w[t]), w[-1] = w[95] = 0
    float w63 = rdlanef(w0, 63);
    float c0 = 0.5f * (dppf<DPP_WF_SR1, 0xF>(w0, 0.0f) + w0);   // t = lane
    float c1 = 0.5f * (dppf<DPP_WF_SR1, 0xF>(w1, w63) + w1);    // t = 64+lane

    // weight / depth reductions: proven shfl_xor butterfly, full-exec region
    float wsum = w0 + w1;
    float dsum = fmaf(w0, mid0, w1 * mid1);      // w1 == mid1 == 0 for lane>=31
    #pragma unroll
    for (int off = 32; off > 0; off >>= 1) {
        wsum += __shfl_xor(wsum, off);
        dsum += __shfl_xor(dsum, off);
    }

    // ---- scan-side stores (coalesced; big streams non-temporal) ----
    const size_t b95 = (size_t)ray * SM1;
    __builtin_nontemporal_store(a0, out_alpha + b95 + lane);
    __builtin_nontemporal_store(w0, out_w + b95 + lane);
    if (hi) {
        __builtin_nontemporal_store(a1, out_alpha + b95 + 64 + lane);
        __builtin_nontemporal_store(w1, out_w + b95 + 64 + lane);
    }
    float dlast = rdlanef(dn1, 30);              // dep[95] (readlane ignores exec)
    if (lane == 0) {
        out_wbg[ray] = wbg;
        float cd = dsum / wsum;
        if (cd != cd) cd = __builtin_inff();     // NaN -> inf; clip in finalize
        out_depth[ray] = cd;
        ws_d0[ray] = dep0;                       // dep[0] (depths sorted)
        ws_d1[ray] = dlast;
    }

    // ---- Phase B: color accumulate ----
    // lane = srow*8 + g; sample t = srow + 8k; float4 index = lane + 64k.
    const int srow = lane >> 3;
    float ax = 0.0f, ay = 0.0f, az = 0.0f, aw = 0.0f;
    #pragma unroll
    for (int k = 0; k < 8; ++k) {
        float c = __shfl(c0, srow + 8 * k);          // t = srow + 8k < 64
        ax = fmaf(c, v[k].x, ax);
        ay = fmaf(c, v[k].y, ay);
        az = fmaf(c, v[k].z, az);
        aw = fmaf(c, v[k].w, aw);
    }
    #pragma unroll
    for (int k = 8; k < 12; ++k) {
        float c = __shfl(c1, srow + 8 * (k - 8));    // t = 64 + srow + 8(k-8)
        ax = fmaf(c, v[k].x, ax);
        ay = fmaf(c, v[k].y, ay);
        az = fmaf(c, v[k].z, az);
        aw = fmaf(c, v[k].w, aw);
    }

    // reduce across the 8 srow groups: ^8 via DPP row_ror:8, then ^16, ^32
    ax += dppf<DPP_ROW_ROR(8), 0xF>(ax, 0.0f);
    ay += dppf<DPP_ROW_ROR(8), 0xF>(ay, 0.0f);
    az += dppf<DPP_ROW_ROR(8), 0xF>(az, 0.0f);
    aw += dppf<DPP_ROW_ROR(8), 0xF>(aw, 0.0f);
    #pragma unroll
    for (int m = 16; m < 64; m <<= 1) {
        ax += __shfl_xor(ax, m);
        ay += __shfl_xor(ay, m);
        az += __shfl_xor(az, m);
        aw += __shfl_xor(aw, m);
    }

    if (lane < 8) {  // g = lane; 8 lanes store 128B contiguous per ray
        float4 o;
        o.x = 2.0f * ax - 1.0f;
        o.y = 2.0f * ay - 1.0f;
        o.z = 2.0f * az - 1.0f;
        o.w = 2.0f * aw - 1.0f;
        ((float4*)(out_rgb + (size_t)ray * NC))[lane] = o;
    }
}

// ---------------------------------------------------------------------------
// Finalize: grid-wide min/max from contiguous workspace endpoints, clip.
// (Round-0 proven structure: coalesced 64 KB streams, L2-resident.)
// ---------------------------------------------------------------------------
__global__ __launch_bounds__(256) void raymarch_finalize(
    const float* __restrict__ ws_d0,
    const float* __restrict__ ws_d1,
    float* __restrict__ out_depth,
    int rays)
{
    __shared__ float s_mn[256];
    __shared__ float s_mx[256];
    const int tid = threadIdx.x;

    float mn = __builtin_inff();
    float mx = -__builtin_inff();
    for (int r = tid; r < rays; r += 256) {
        mn = fminf(mn, ws_d0[r]);
        mx = fmaxf(mx, ws_d1[r]);
    }
    s_mn[tid] = mn;
    s_mx[tid] = mx;
    __syncthreads();
    for (int off = 128; off > 0; off >>= 1) {
        if (tid < off) {
            s_mn[tid] = fminf(s_mn[tid], s_mn[tid + off]);
            s_mx[tid] = fmaxf(s_mx[tid], s_mx[tid + off]);
        }
        __syncthreads();
    }
    const float dmin = s_mn[0];
    const float dmax = s_mx[0];

    const int r = blockIdx.x * 256 + tid;
    if (r < rays) {
        float cd = out_depth[r];
        out_depth[r] = fminf(fmaxf(cd, dmin), dmax);  // clip(inf) -> dmax
    }
}

extern "C" void kernel_launch(void* const* d_in, const int* in_sizes, int n_in,
                              void* d_out, int out_size, void* d_ws, size_t ws_size,
                              hipStream_t stream) {
    (void)n_in; (void)out_size; (void)ws_size;

    const float* colors    = (const float*)d_in[0];
    const float* densities = (const float*)d_in[1];
    const float* depths    = (const float*)d_in[2];

    const int rays = in_sizes[2] / NS;  // B*R = 16384

    float* out = (float*)d_out;
    float* out_rgb   = out;                                   // rays*32
    float* out_depth = out_rgb + (size_t)rays * NC;           // rays
    float* out_w     = out_depth + rays;                      // rays*95
    float* out_alpha = out_w + (size_t)rays * SM1;            // rays*95
    float* out_wbg   = out_alpha + (size_t)rays * SM1;        // rays

    float* ws    = (float*)d_ws;
    float* ws_d0 = ws;                                        // rays
    float* ws_d1 = ws + rays;                                 // rays

    raymarch_fused<<<rays / 4, 256, 0, stream>>>(
        colors, densities, depths,
        out_rgb, out_depth, out_w, out_alpha, out_wbg, ws_d0, ws_d1);

    raymarch_finalize<<<(rays + 255) / 256, 256, 0, stream>>>(
        ws_d0, ws_d1, out_depth, rays);
}